// Round 3
// baseline (312.604 us; speedup 1.0000x reference)
//
#include <hip/hip_runtime.h>
#include <math.h>

// Problem constants (fixed by the reference)
#define NBATCH 16
#define CCH    128     // channels C
#define HW     2304    // 48*48 tokens per frame
#define DI     64      // inter_channels CI
#define NTILE  36      // HW / 64
#define KSTR   72      // K LDS row stride (u16)
#define PSTR   76      // P LDS row stride (u16) — conflict-free b16 writes

typedef unsigned short u16;
typedef unsigned int   u32;
typedef __bf16 bf16x8 __attribute__((ext_vector_type(8)));
typedef __bf16 bf16x4 __attribute__((ext_vector_type(4)));
typedef float  f32x4  __attribute__((ext_vector_type(4)));

__device__ __forceinline__ u16 f2bf_rne(float x) {
    union { float f; u32 u; } v; v.f = x;
    u32 r = (v.u + 0x7FFFu + ((v.u >> 16) & 1u)) >> 16;
    return (u16)r;
}

// ---------------------------------------------------------------------------
// Kernel 1: fused q/k/v projection -> bf16. W staged in 32-channel chunks
// (27.6 KB LDS, was 101 KB -> occupancy fix).
// q,k stored [n][p][d]; v stored TRANSPOSED [n][d][p].
// ---------------------------------------------------------------------------
__global__ __launch_bounds__(256) void proj_kernel(
    const float* __restrict__ F,
    const float* __restrict__ Wq, const float* __restrict__ bq,
    const float* __restrict__ Wk, const float* __restrict__ bk,
    const float* __restrict__ Wv, const float* __restrict__ bv,
    u16* __restrict__ qo, u16* __restrict__ ko, u16* __restrict__ vto)
{
    __shared__ __align__(16) float Ws[3][DI][36];   // 27648 B
    const int tid  = threadIdx.x;
    const int n    = blockIdx.x / NTILE;
    const int p0   = (blockIdx.x % NTILE) * 64;
    const int lane = tid & 63;                                   // = d
    const int wave = tid >> 6;
    const float* Fn = F + (size_t)n * CCH * HW;

    float aq[16], ak[16], av[16];
    const float bq_ = bq[lane], bk_ = bk[lane], bv_ = bv[lane];
    #pragma unroll
    for (int i = 0; i < 16; ++i) { aq[i] = bq_; ak[i] = bk_; av[i] = bv_; }

    const int pbase = p0 + wave * 16;
    for (int ch = 0; ch < 4; ++ch) {
        __syncthreads();                       // previous chunk fully consumed
        for (int idx = tid; idx < DI * 32; idx += 256) {
            int d = idx >> 5, cc = idx & 31;
            int gsrc = d * CCH + ch * 32 + cc;
            Ws[0][d][cc] = Wq[gsrc];
            Ws[1][d][cc] = Wk[gsrc];
            Ws[2][d][cc] = Wv[gsrc];
        }
        __syncthreads();
        for (int c4 = 0; c4 < 8; ++c4) {
            float4 wq4 = *(const float4*)&Ws[0][lane][c4 * 4];
            float4 wk4 = *(const float4*)&Ws[1][lane][c4 * 4];
            float4 wv4 = *(const float4*)&Ws[2][lane][c4 * 4];
            const float* F0 = Fn + (size_t)(ch * 32 + c4 * 4) * HW + pbase;
            #pragma unroll
            for (int i = 0; i < 16; ++i) {
                float f0 = F0[i];
                float f1 = F0[HW + i];
                float f2 = F0[2 * HW + i];
                float f3 = F0[3 * HW + i];
                aq[i] += f0 * wq4.x + f1 * wq4.y + f2 * wq4.z + f3 * wq4.w;
                ak[i] += f0 * wk4.x + f1 * wk4.y + f2 * wk4.z + f3 * wk4.w;
                av[i] += f0 * wv4.x + f1 * wv4.y + f2 * wv4.z + f3 * wv4.w;
            }
        }
    }
    #pragma unroll
    for (int i = 0; i < 16; ++i) {
        size_t off = (size_t)(n * HW + pbase + i) * DI + lane;   // coalesced (d=lane)
        qo[off] = f2bf_rne(aq[i]);
        ko[off] = f2bf_rne(ak[i]);
    }
    union { u16 s[16]; uint4 v[2]; } pk;
    #pragma unroll
    for (int i = 0; i < 16; ++i) pk.s[i] = f2bf_rne(av[i]);
    size_t vo_off = ((size_t)n * DI + lane) * HW + pbase;
    *(uint4*)&vto[vo_off]     = pk.v[0];
    *(uint4*)&vto[vo_off + 8] = pk.v[1];
}

// ---------------------------------------------------------------------------
// Kernel 2: one-pass MFMA flash attention (no-max softmax). Block = (pass,
// frame, 64 q-rows); grid 1152. K double-buffered in LDS (1 barrier/tile),
// V-frags read directly from L2 (frame V^T is XCD-L2-resident via swizzle).
// Writes per-pass normalized y (bf16) to ypart.
// ---------------------------------------------------------------------------
__global__ __launch_bounds__(256, 4) void attn_pass_kernel(
    const u16* __restrict__ q, const u16* __restrict__ k, const u16* __restrict__ vt,
    u16* __restrict__ ypart)
{
    __shared__ __align__(16) u16 Kbuf[2][64 * KSTR];   // 18432 B
    __shared__ __align__(16) u16 Pbuf[4][16 * PSTR];   //  9728 B

    const int tid  = threadIdx.x;
    const int lane = tid & 63;
    const int wave = tid >> 6;
    const int lo   = lane & 15, hi = lane >> 4;

    // chunked bijective XCD swizzle: 1152 = 8 * 144
    const int bid  = (int)blockIdx.x;
    const int w    = (bid & 7) * 144 + (bid >> 3);
    const int pass = w / (NBATCH * NTILE);
    const int rem  = w % (NBATCH * NTILE);
    const int n    = rem / NTILE;
    const int p0   = (rem % NTILE) * 64;

    const int nb = (pass == 0) ? (n > 0 ? n - 1 : 0)
                               : (n < NBATCH - 1 ? n + 1 : n);
    const u16* kp = k  + (size_t)nb * HW * DI;
    const u16* vp = vt + (size_t)nb * DI * HW;

    // Q fragments (A-layout): lane holds Q[q=lo][d=hi*8+j]
    bf16x8 qf0, qf1;
    {
        const u16* qp = q + ((size_t)n * HW + p0 + wave * 16 + lo) * DI + hi * 8;
        qf0 = *(const bf16x8*)qp;
        qf1 = *(const bf16x8*)(qp + 32);
    }

    u16* Pw = Pbuf[wave];

    // K staging: thread covers rows tid>>3, tid>>3+32 (16B each)
    const int srow0 = tid >> 3;
    const int srow1 = srow0 + 32;
    const int scol  = (tid & 7) * 8;

    f32x4 yacc[4];
    float lacc[4] = {0.f, 0.f, 0.f, 0.f};
    #pragma unroll
    for (int nf = 0; nf < 4; ++nf)
        #pragma unroll
        for (int r = 0; r < 4; ++r) yacc[nf][r] = 0.f;

    // prologue: tile 0 -> Kbuf[0], prefetch tile 1 into regs
    uint4 k0 = *(const uint4*)(kp + (size_t)srow0 * DI + scol);
    uint4 k1 = *(const uint4*)(kp + (size_t)srow1 * DI + scol);
    *(uint4*)&Kbuf[0][srow0 * KSTR + scol] = k0;
    *(uint4*)&Kbuf[0][srow1 * KSTR + scol] = k1;
    k0 = *(const uint4*)(kp + (size_t)(64 + srow0) * DI + scol);
    k1 = *(const uint4*)(kp + (size_t)(64 + srow1) * DI + scol);
    __syncthreads();

    auto tile_body = [&](int t, int cur) {
        // V frags direct from global (L2 hit); issued before QK so the
        // ~200-cycle L2 latency hides under QK^T + exp.
        bf16x8 vf[4][2];
        #pragma unroll
        for (int nf = 0; nf < 4; ++nf)
            #pragma unroll
            for (int ks = 0; ks < 2; ++ks)
                vf[nf][ks] = *(const bf16x8*)(vp + (size_t)(nf * 16 + lo) * HW
                                              + t * 64 + ks * 32 + hi * 8);

        // --- QK^T: S[16 q][64 key] ---
        f32x4 sacc[4];
        #pragma unroll
        for (int nf = 0; nf < 4; ++nf) {
            f32x4 z = {0.f, 0.f, 0.f, 0.f};
            bf16x8 kf0 = *(const bf16x8*)&Kbuf[cur][(nf * 16 + lo) * KSTR + hi * 8];
            bf16x8 kf1 = *(const bf16x8*)&Kbuf[cur][(nf * 16 + lo) * KSTR + 32 + hi * 8];
            z = __builtin_amdgcn_mfma_f32_16x16x32_bf16(qf0, kf0, z, 0, 0, 0);
            z = __builtin_amdgcn_mfma_f32_16x16x32_bf16(qf1, kf1, z, 0, 0, 0);
            sacc[nf] = z;
        }

        // --- P = exp(S); l from bf16-rounded P (self-normalizing) ---
        #pragma unroll
        for (int nf = 0; nf < 4; ++nf) {
            #pragma unroll
            for (int r = 0; r < 4; ++r) {
                union { float f; u32 u; } cv;
                cv.f = __expf(sacc[nf][r]);
                u16 pb = (u16)(cv.u >> 16);       // truncate to bf16
                cv.u = (u32)pb << 16;
                lacc[r] += cv.f;
                Pw[(hi * 4 + r) * PSTR + nf * 16 + lo] = pb;
            }
        }

        // --- P read (b64 pairs; stride 76 keeps 8B alignment) + PV ---
        bf16x4 a0 = *(const bf16x4*)&Pw[lo * PSTR + hi * 8];
        bf16x4 a1 = *(const bf16x4*)&Pw[lo * PSTR + hi * 8 + 4];
        bf16x4 b0 = *(const bf16x4*)&Pw[lo * PSTR + 32 + hi * 8];
        bf16x4 b1 = *(const bf16x4*)&Pw[lo * PSTR + 32 + hi * 8 + 4];
        bf16x8 pa0, pa1;
        #pragma unroll
        for (int j = 0; j < 4; ++j) {
            pa0[j] = a0[j]; pa0[j + 4] = a1[j];
            pa1[j] = b0[j]; pa1[j + 4] = b1[j];
        }
        #pragma unroll
        for (int nf = 0; nf < 4; ++nf) {
            yacc[nf] = __builtin_amdgcn_mfma_f32_16x16x32_bf16(pa0, vf[nf][0], yacc[nf], 0, 0, 0);
            yacc[nf] = __builtin_amdgcn_mfma_f32_16x16x32_bf16(pa1, vf[nf][1], yacc[nf], 0, 0, 0);
        }

        // stage next K tile into the other buffer (race-free: nobody reads
        // buf^1 until the barrier below; everybody finished reading it at the
        // previous barrier).
        if (t + 1 < NTILE) {
            *(uint4*)&Kbuf[cur ^ 1][srow0 * KSTR + scol] = k0;
            *(uint4*)&Kbuf[cur ^ 1][srow1 * KSTR + scol] = k1;
        }
        if (t + 2 < NTILE) {
            k0 = *(const uint4*)(kp + (size_t)((t + 2) * 64 + srow0) * DI + scol);
            k1 = *(const uint4*)(kp + (size_t)((t + 2) * 64 + srow1) * DI + scol);
        }
        __syncthreads();
    };

    #pragma unroll 1
    for (int tt = 0; tt < NTILE; tt += 2) {
        tile_body(tt, 0);
        tile_body(tt + 1, 1);
    }

    // l reduce across key-lanes (lo), normalize, restage via LDS, store
    float inv[4];
    #pragma unroll
    for (int r = 0; r < 4; ++r) {
        float l = lacc[r];
        l += __shfl_xor(l, 1);
        l += __shfl_xor(l, 2);
        l += __shfl_xor(l, 4);
        l += __shfl_xor(l, 8);
        inv[r] = 1.f / l;
    }
    u16* yw = (u16*)Kbuf;                          // [64][KSTR] bf16
    #pragma unroll
    for (int nf = 0; nf < 4; ++nf)
        #pragma unroll
        for (int r = 0; r < 4; ++r)
            yw[(wave * 16 + hi * 4 + r) * KSTR + nf * 16 + lo] =
                f2bf_rne(yacc[nf][r] * inv[r]);
    __syncthreads();

    u16* yg = ypart + ((size_t)(pass * NBATCH + n) * HW + p0) * DI;
    #pragma unroll
    for (int s = 0; s < 2; ++s) {
        int idx = tid + s * 256;                   // 512 x 16B chunks
        int row = idx >> 3, c8 = (idx & 7) * 8;
        *(uint4*)&yg[row * DI + c8] = *(const uint4*)&yw[row * KSTR + c8];
    }
}

// ---------------------------------------------------------------------------
// Kernel 3: combine passes + fused z-projection + residual.
// z = (y_b + y_a) @ Wz^T + 2*bz + F
// ---------------------------------------------------------------------------
__global__ __launch_bounds__(256) void combine_kernel(
    const u16* __restrict__ ypart, const float* __restrict__ Wz,
    const float* __restrict__ bz, const float* __restrict__ F,
    float* __restrict__ out)
{
    __shared__ __align__(16) float ys[64 * 68];
    const int tid = threadIdx.x;
    const int n   = blockIdx.x / NTILE;
    const int p0  = (blockIdx.x % NTILE) * 64;
    const u16* y0 = ypart + ((size_t)n * HW + p0) * DI;
    const u16* y1 = ypart + ((size_t)(NBATCH + n) * HW + p0) * DI;

    #pragma unroll
    for (int s = 0; s < 2; ++s) {
        int idx = tid + s * 256;
        int row = idx >> 3, c8 = (idx & 7) * 8;
        uint4 a = *(const uint4*)&y0[row * DI + c8];
        uint4 b = *(const uint4*)&y1[row * DI + c8];
        const u32 au[4] = {a.x, a.y, a.z, a.w};
        const u32 bu[4] = {b.x, b.y, b.z, b.w};
        float* d = &ys[row * 68 + c8];
        #pragma unroll
        for (int e = 0; e < 4; ++e) {
            union { u32 u; float f; } la, ha, lb, hb;
            la.u = au[e] << 16;          ha.u = au[e] & 0xFFFF0000u;
            lb.u = bu[e] << 16;          hb.u = bu[e] & 0xFFFF0000u;
            d[e * 2]     = la.f + lb.f;
            d[e * 2 + 1] = ha.f + hb.f;
        }
    }
    __syncthreads();

    const int lane = tid & 63;
    const int wave = tid >> 6;
    float acc[32];
    #pragma unroll
    for (int i = 0; i < 32; ++i) acc[i] = 0.f;
    #pragma unroll
    for (int d4 = 0; d4 < 16; ++d4) {
        float4 yy = *(const float4*)&ys[lane * 68 + d4 * 4];
        #pragma unroll 8
        for (int i = 0; i < 32; ++i) {
            int c = wave + 4 * i;                  // wave-uniform -> scalar Wz loads
            float4 ww = *(const float4*)&Wz[c * DI + d4 * 4];
            acc[i] += yy.x * ww.x + yy.y * ww.y + yy.z * ww.z + yy.w * ww.w;
        }
    }
    #pragma unroll 4
    for (int i = 0; i < 32; ++i) {
        int c = wave + 4 * i;
        size_t gi = (size_t)(n * CCH + c) * HW + p0 + lane;
        out[gi] = acc[i] + 2.f * bz[c] + F[gi];    // coalesced store + residual
    }
}

extern "C" void kernel_launch(void* const* d_in, const int* in_sizes, int n_in,
                              void* d_out, int out_size, void* d_ws, size_t ws_size,
                              hipStream_t stream) {
    const float* F  = (const float*)d_in[0];
    const float* Wq = (const float*)d_in[1];
    const float* bq = (const float*)d_in[2];
    const float* Wk = (const float*)d_in[3];
    const float* bk = (const float*)d_in[4];
    const float* Wv = (const float*)d_in[5];
    const float* bv = (const float*)d_in[6];
    const float* Wz = (const float*)d_in[7];
    const float* bz = (const float*)d_in[8];
    float* outp = (float*)d_out;

    const size_t tok = (size_t)NBATCH * HW * DI;   // 2,359,296 elements
    u16* qb  = (u16*)d_ws;
    u16* kb  = qb  + tok;
    u16* vtb = kb  + tok;
    u16* yp  = vtb + tok;                          // 2*tok bf16 partials
    // total ws: 5 * tok * 2B = 23.6 MB

    proj_kernel<<<NBATCH * NTILE, 256, 0, stream>>>(F, Wq, bq, Wk, bk, Wv, bv, qb, kb, vtb);
    attn_pass_kernel<<<2 * NBATCH * NTILE, 256, 0, stream>>>(qb, kb, vtb, yp);
    combine_kernel<<<NBATCH * NTILE, 256, 0, stream>>>(yp, Wz, bz, F, outp);
}

// Round 5
// 205.053 us; speedup vs baseline: 1.5245x; 1.5245x over previous
//
#include <hip/hip_runtime.h>
#include <math.h>

// Problem constants (fixed by the reference)
#define NBATCH 16
#define CCH    128     // channels C
#define HW     2304    // 48*48 tokens per frame
#define DI     64      // inter_channels CI
#define NTILE  36      // HW / 64

typedef unsigned short u16;
typedef unsigned int   u32;
typedef __bf16 bf16x8 __attribute__((ext_vector_type(8)));
typedef float  f32x4  __attribute__((ext_vector_type(4)));

union W4 { u32 w[4]; bf16x8 v; };

__device__ __forceinline__ u16 f2bf_rne(float x) {
    union { float f; u32 u; } v; v.f = x;
    u32 r = (v.u + 0x7FFFu + ((v.u >> 16) & 1u)) >> 16;
    return (u16)r;
}
__device__ __forceinline__ float bfval(u16 b) { union { u32 u; float f; } c; c.u = (u32)b << 16; return c.f; }
__device__ __forceinline__ float bflo(u32 w) { union { u32 u; float f; } c; c.u = w << 16;         return c.f; }
__device__ __forceinline__ float bfhi(u32 w) { union { u32 u; float f; } c; c.u = w & 0xFFFF0000u; return c.f; }

// ---------------------------------------------------------------------------
// Kernel 1: fused q/k/v projection -> bf16 (chunked W staging, 27.6 KB LDS).
// q,k stored [n][p][d]; v stored TRANSPOSED [n][d][p].   (validated round 3)
// ---------------------------------------------------------------------------
__global__ __launch_bounds__(256) void proj_kernel(
    const float* __restrict__ F,
    const float* __restrict__ Wq, const float* __restrict__ bq,
    const float* __restrict__ Wk, const float* __restrict__ bk,
    const float* __restrict__ Wv, const float* __restrict__ bv,
    u16* __restrict__ qo, u16* __restrict__ ko, u16* __restrict__ vto)
{
    __shared__ __align__(16) float Ws[3][DI][36];   // 27648 B
    const int tid  = threadIdx.x;
    const int n    = blockIdx.x / NTILE;
    const int p0   = (blockIdx.x % NTILE) * 64;
    const int lane = tid & 63;                                   // = d
    const int wave = tid >> 6;
    const float* Fn = F + (size_t)n * CCH * HW;

    float aq[16], ak[16], av[16];
    const float bq_ = bq[lane], bk_ = bk[lane], bv_ = bv[lane];
    #pragma unroll
    for (int i = 0; i < 16; ++i) { aq[i] = bq_; ak[i] = bk_; av[i] = bv_; }

    const int pbase = p0 + wave * 16;
    for (int ch = 0; ch < 4; ++ch) {
        __syncthreads();
        for (int idx = tid; idx < DI * 32; idx += 256) {
            int d = idx >> 5, cc = idx & 31;
            int gsrc = d * CCH + ch * 32 + cc;
            Ws[0][d][cc] = Wq[gsrc];
            Ws[1][d][cc] = Wk[gsrc];
            Ws[2][d][cc] = Wv[gsrc];
        }
        __syncthreads();
        for (int c4 = 0; c4 < 8; ++c4) {
            float4 wq4 = *(const float4*)&Ws[0][lane][c4 * 4];
            float4 wk4 = *(const float4*)&Ws[1][lane][c4 * 4];
            float4 wv4 = *(const float4*)&Ws[2][lane][c4 * 4];
            const float* F0 = Fn + (size_t)(ch * 32 + c4 * 4) * HW + pbase;
            #pragma unroll
            for (int i = 0; i < 16; ++i) {
                float f0 = F0[i];
                float f1 = F0[HW + i];
                float f2 = F0[2 * HW + i];
                float f3 = F0[3 * HW + i];
                aq[i] += f0 * wq4.x + f1 * wq4.y + f2 * wq4.z + f3 * wq4.w;
                ak[i] += f0 * wk4.x + f1 * wk4.y + f2 * wk4.z + f3 * wk4.w;
                av[i] += f0 * wv4.x + f1 * wv4.y + f2 * wv4.z + f3 * wv4.w;
            }
        }
    }
    #pragma unroll
    for (int i = 0; i < 16; ++i) {
        size_t off = (size_t)(n * HW + pbase + i) * DI + lane;   // coalesced (d=lane)
        qo[off] = f2bf_rne(aq[i]);
        ko[off] = f2bf_rne(ak[i]);
    }
    union { u16 s[16]; uint4 v[2]; } pk;
    #pragma unroll
    for (int i = 0; i < 16; ++i) pk.s[i] = f2bf_rne(av[i]);
    size_t vo_off = ((size_t)n * DI + lane) * HW + pbase;
    *(uint4*)&vto[vo_off]     = pk.v[0];
    *(uint4*)&vto[vo_off + 8] = pk.v[1];
}

// ---------------------------------------------------------------------------
// Kernel 2: one-pass MFMA flash attention (no-max softmax). P stays entirely
// in registers WITHOUT cross-lane moves: the K A-fragment rows are loaded
// through the permutation kr_m(l) = 8(l>>2)+(l&3)+4(m&1)+32(m>>1), so the
// QK^T C-layout lands S[key=8hi+4(m&1)+r+32(m>>1)][q=lo] in each lane —
// exactly the keys 8hi..8hi+7 (resp. +32) that lane's PV A-frag needs.
// K,V double-buffered in swizzled LDS, one barrier per tile.
// K-tile swizzle fK(row)=(row&3)|((row&8)>>1)  (fK(kr_m(lo)) = lo&7,
// conflict-free for both staging and the permuted frag reads);
// V-tile swizzle row&7.
// Block = (pass, frame, 64 q-rows); grid 1152.
// ---------------------------------------------------------------------------
__global__ __launch_bounds__(256, 4) void attn_pass_kernel(
    const u16* __restrict__ q, const u16* __restrict__ k, const u16* __restrict__ vt,
    u16* __restrict__ ypart)
{
    __shared__ __align__(16) u16 smem[16384];     // 32 KiB: K dbuf | V dbuf
    u16* const Kb0 = smem;
    u16* const Kb1 = smem + 4096;
    u16* const Vb0 = smem + 8192;
    u16* const Vb1 = smem + 12288;

    const int tid  = threadIdx.x;
    const int lane = tid & 63;
    const int wave = tid >> 6;
    const int lo   = lane & 15, hi = lane >> 4;

    // chunked bijective XCD swizzle: 1152 = 8 * 144
    const int bid  = (int)blockIdx.x;
    const int w    = (bid & 7) * 144 + (bid >> 3);
    const int pass = w / (NBATCH * NTILE);
    const int rem  = w % (NBATCH * NTILE);
    const int n    = rem / NTILE;
    const int p0   = (rem % NTILE) * 64;

    const int nb = (pass == 0) ? (n > 0 ? n - 1 : 0)
                               : (n < NBATCH - 1 ? n + 1 : n);
    const u16* kp = k  + (size_t)nb * HW * DI;
    const u16* vp = vt + (size_t)nb * DI * HW;

    // Q fragments (B-operand of swapped QK): lane holds Q[q=lo][d=hi*8+j]
    bf16x8 qf0, qf1;
    {
        const u16* qp = q + ((size_t)n * HW + p0 + wave * 16 + lo) * DI + hi * 8;
        qf0 = *(const bf16x8*)qp;
        qf1 = *(const bf16x8*)(qp + 32);
    }

    // staging geometry: 512 x 16B chunks per 8KB tile; thread covers 2 rows
    const int sch   = tid & 7;                 // 16B chunk in row
    const int srow0 = tid >> 3;                // 0..31
    const int srow1 = srow0 + 32;
    const int fk0   = (srow0 & 3) | ((srow0 & 8) >> 1);
    const int fk1   = (srow1 & 3) | ((srow1 & 8) >> 1);
    const int koff0 = srow0 * 64 + ((sch ^ fk0) * 8);
    const int koff1 = srow1 * 64 + ((sch ^ fk1) * 8);
    const int voff0 = srow0 * 64 + ((sch ^ (srow0 & 7)) * 8);
    const int voff1 = srow1 * 64 + ((sch ^ (srow1 & 7)) * 8);

    // permuted K A-frag row base: kr_m = krbase + 4*(m&1) + 32*(m>>1)
    const int krbase = 8 * (lo >> 2) + (lo & 3);
    const int xl = lo & 7;                     // = fK(kr_m(lo)) = (V row)&7

    f32x4 yacc[4];
    #pragma unroll
    for (int nf = 0; nf < 4; ++nf)
        #pragma unroll
        for (int r = 0; r < 4; ++r) yacc[nf][r] = 0.f;
    float lacc = 0.f;

    // prologue: tile0 -> buf0; tile1 -> regs
    uint4 ka0 = *(const uint4*)(kp + (size_t)srow0 * DI + sch * 8);
    uint4 ka1 = *(const uint4*)(kp + (size_t)srow1 * DI + sch * 8);
    uint4 va0 = *(const uint4*)(vp + (size_t)srow0 * HW + sch * 8);
    uint4 va1 = *(const uint4*)(vp + (size_t)srow1 * HW + sch * 8);
    *(uint4*)&Kb0[koff0] = ka0;  *(uint4*)&Kb0[koff1] = ka1;
    *(uint4*)&Vb0[voff0] = va0;  *(uint4*)&Vb0[voff1] = va1;
    ka0 = *(const uint4*)(kp + (size_t)(64 + srow0) * DI + sch * 8);
    ka1 = *(const uint4*)(kp + (size_t)(64 + srow1) * DI + sch * 8);
    va0 = *(const uint4*)(vp + (size_t)srow0 * HW + 64 + sch * 8);
    va1 = *(const uint4*)(vp + (size_t)srow1 * HW + 64 + sch * 8);
    __syncthreads();

    auto body = [&](int t, const u16* Kc, const u16* Vc, u16* Kn, u16* Vn) {
        // --- swapped QK^T with permuted A rows ---
        // st[m][r] = S[key = 8hi + 4(m&1) + r + 32(m>>1)][q = lo]
        f32x4 st[4];
        #pragma unroll
        for (int m = 0; m < 4; ++m) {
            const int kr = krbase + 4 * (m & 1) + 32 * (m >> 1);
            bf16x8 a0 = *(const bf16x8*)&Kc[kr * 64 + ((hi ^ xl) * 8)];
            bf16x8 a1 = *(const bf16x8*)&Kc[kr * 64 + (((4 + hi) ^ xl) * 8)];
            f32x4 z = {0.f, 0.f, 0.f, 0.f};
            z = __builtin_amdgcn_mfma_f32_16x16x32_bf16(a0, qf0, z, 0, 0, 0);
            z = __builtin_amdgcn_mfma_f32_16x16x32_bf16(a1, qf1, z, 0, 0, 0);
            st[m] = z;
        }

        // --- P = exp(S), bf16 RNE pack in place (A-frag order);
        //     l accumulated from the rounded values (self-normalizing) ---
        W4 pa0, pa1;
        #pragma unroll
        for (int m = 0; m < 4; ++m) {
            u16 b0 = f2bf_rne(__expf(st[m][0]));
            u16 b1 = f2bf_rne(__expf(st[m][1]));
            u16 b2 = f2bf_rne(__expf(st[m][2]));
            u16 b3 = f2bf_rne(__expf(st[m][3]));
            lacc += (bfval(b0) + bfval(b1)) + (bfval(b2) + bfval(b3));
            u32 we = (u32)b0 | ((u32)b1 << 16);
            u32 wo = (u32)b2 | ((u32)b3 << 16);
            if (m == 0)      { pa0.w[0] = we; pa0.w[1] = wo; }
            else if (m == 1) { pa0.w[2] = we; pa0.w[3] = wo; }
            else if (m == 2) { pa1.w[0] = we; pa1.w[1] = wo; }
            else             { pa1.w[2] = we; pa1.w[3] = wo; }
        }

        // --- PV: Y[q][d] += P(16x64) x V(64k x 64d)  (B from V^T tile) ---
        #pragma unroll
        for (int nf = 0; nf < 4; ++nf) {
            const int vr = nf * 16 + lo;
            bf16x8 v0 = *(const bf16x8*)&Vc[vr * 64 + ((hi ^ xl) * 8)];
            bf16x8 v1 = *(const bf16x8*)&Vc[vr * 64 + (((4 + hi) ^ xl) * 8)];
            yacc[nf] = __builtin_amdgcn_mfma_f32_16x16x32_bf16(pa0.v, v0, yacc[nf], 0, 0, 0);
            yacc[nf] = __builtin_amdgcn_mfma_f32_16x16x32_bf16(pa1.v, v1, yacc[nf], 0, 0, 0);
        }

        // --- stage tile t+1 into the other buffer; prefetch t+2 ---
        if (t + 1 < NTILE) {
            *(uint4*)&Kn[koff0] = ka0; *(uint4*)&Kn[koff1] = ka1;
            *(uint4*)&Vn[voff0] = va0; *(uint4*)&Vn[voff1] = va1;
        }
        if (t + 2 < NTILE) {
            int tb = (t + 2) * 64;
            ka0 = *(const uint4*)(kp + (size_t)(tb + srow0) * DI + sch * 8);
            ka1 = *(const uint4*)(kp + (size_t)(tb + srow1) * DI + sch * 8);
            va0 = *(const uint4*)(vp + (size_t)srow0 * HW + tb + sch * 8);
            va1 = *(const uint4*)(vp + (size_t)srow1 * HW + tb + sch * 8);
        }
        __syncthreads();
    };

    #pragma unroll 1
    for (int tt = 0; tt < NTILE; tt += 2) {
        body(tt,     Kb0, Vb0, Kb1, Vb1);
        body(tt + 1, Kb1, Vb1, Kb0, Vb0);
    }

    // --- finalize: per-lane lacc covers keys {8hi..8hi+7, 32+8hi..} at q=lo;
    //     reduce over the hi dimension -> full l(q=lo) ---
    float l = lacc;
    l += __shfl_xor(l, 16);
    l += __shfl_xor(l, 32);
    float inv = 1.f / l;                       // valid for q = lo at every lane
    float invq[4];
    #pragma unroll
    for (int r = 0; r < 4; ++r) invq[r] = __shfl(inv, 20 * hi + r);  // q = 4hi+r

    __syncthreads();                           // done with K/V buffers
    u16* yw = smem;                            // [64][72] bf16 restage
    #pragma unroll
    for (int nf = 0; nf < 4; ++nf)
        #pragma unroll
        for (int r = 0; r < 4; ++r)
            yw[(wave * 16 + hi * 4 + r) * 72 + nf * 16 + lo] =
                f2bf_rne(yacc[nf][r] * invq[r]);
    __syncthreads();

    u16* yg = ypart + ((size_t)(pass * NBATCH + n) * HW + p0) * DI;
    #pragma unroll
    for (int s = 0; s < 2; ++s) {
        int idx = tid + s * 256;
        int row = idx >> 3, c8 = (idx & 7) * 8;
        *(uint4*)&yg[row * DI + c8] = *(const uint4*)&yw[row * 72 + c8];
    }
}

// ---------------------------------------------------------------------------
// Kernel 3: combine passes + fused z-projection + residual.
// z = (y_b + y_a) @ Wz^T + 2*bz + F                     (validated round 3)
// ---------------------------------------------------------------------------
__global__ __launch_bounds__(256) void combine_kernel(
    const u16* __restrict__ ypart, const float* __restrict__ Wz,
    const float* __restrict__ bz, const float* __restrict__ F,
    float* __restrict__ out)
{
    __shared__ __align__(16) float ys[64 * 68];
    const int tid = threadIdx.x;
    const int n   = blockIdx.x / NTILE;
    const int p0  = (blockIdx.x % NTILE) * 64;
    const u16* y0 = ypart + ((size_t)n * HW + p0) * DI;
    const u16* y1 = ypart + ((size_t)(NBATCH + n) * HW + p0) * DI;

    #pragma unroll
    for (int s = 0; s < 2; ++s) {
        int idx = tid + s * 256;
        int row = idx >> 3, c8 = (idx & 7) * 8;
        uint4 a = *(const uint4*)&y0[row * DI + c8];
        uint4 b = *(const uint4*)&y1[row * DI + c8];
        const u32 au[4] = {a.x, a.y, a.z, a.w};
        const u32 bu[4] = {b.x, b.y, b.z, b.w};
        float* d = &ys[row * 68 + c8];
        #pragma unroll
        for (int e = 0; e < 4; ++e) {
            d[e * 2]     = bflo(au[e]) + bflo(bu[e]);
            d[e * 2 + 1] = bfhi(au[e]) + bfhi(bu[e]);
        }
    }
    __syncthreads();

    const int lane = tid & 63;
    const int wave = tid >> 6;
    float acc[32];
    #pragma unroll
    for (int i = 0; i < 32; ++i) acc[i] = 0.f;
    #pragma unroll
    for (int d4 = 0; d4 < 16; ++d4) {
        float4 yy = *(const float4*)&ys[lane * 68 + d4 * 4];
        #pragma unroll 8
        for (int i = 0; i < 32; ++i) {
            int c = wave + 4 * i;                  // wave-uniform -> scalar Wz loads
            float4 ww = *(const float4*)&Wz[c * DI + d4 * 4];
            acc[i] += yy.x * ww.x + yy.y * ww.y + yy.z * ww.z + yy.w * ww.w;
        }
    }
    #pragma unroll 4
    for (int i = 0; i < 32; ++i) {
        int c = wave + 4 * i;
        size_t gi = (size_t)(n * CCH + c) * HW + p0 + lane;
        out[gi] = acc[i] + 2.f * bz[c] + F[gi];    // coalesced store + residual
    }
}

extern "C" void kernel_launch(void* const* d_in, const int* in_sizes, int n_in,
                              void* d_out, int out_size, void* d_ws, size_t ws_size,
                              hipStream_t stream) {
    const float* F  = (const float*)d_in[0];
    const float* Wq = (const float*)d_in[1];
    const float* bq = (const float*)d_in[2];
    const float* Wk = (const float*)d_in[3];
    const float* bk = (const float*)d_in[4];
    const float* Wv = (const float*)d_in[5];
    const float* bv = (const float*)d_in[6];
    const float* Wz = (const float*)d_in[7];
    const float* bz = (const float*)d_in[8];
    float* outp = (float*)d_out;

    const size_t tok = (size_t)NBATCH * HW * DI;   // 2,359,296 elements
    u16* qb  = (u16*)d_ws;
    u16* kb  = qb  + tok;
    u16* vtb = kb  + tok;
    u16* yp  = vtb + tok;                          // 2*tok bf16 partials
    // total ws: 5 * tok * 2B = 23.6 MB

    proj_kernel<<<NBATCH * NTILE, 256, 0, stream>>>(F, Wq, bq, Wk, bk, Wv, bv, qb, kb, vtb);
    attn_pass_kernel<<<2 * NBATCH * NTILE, 256, 0, stream>>>(qb, kb, vtb, yp);
    combine_kernel<<<NBATCH * NTILE, 256, 0, stream>>>(yp, Wz, bz, F, outp);
}

// Round 6
// 197.686 us; speedup vs baseline: 1.5813x; 1.0373x over previous
//
#include <hip/hip_runtime.h>
#include <math.h>

// Problem constants (fixed by the reference)
#define NBATCH 16
#define CCH    128     // channels C
#define HW     2304    // 48*48 tokens per frame
#define DI     64      // inter_channels CI
#define NTILE  36      // HW / 64

typedef unsigned short u16;
typedef unsigned int   u32;
typedef __bf16 bf16x8 __attribute__((ext_vector_type(8)));
typedef float  f32x4  __attribute__((ext_vector_type(4)));

union W4 { u32 w[4]; bf16x8 v; };

__device__ __forceinline__ u16 f2bf_rne(float x) {
    union { float f; u32 u; } v; v.f = x;
    u32 r = (v.u + 0x7FFFu + ((v.u >> 16) & 1u)) >> 16;
    return (u16)r;
}
__device__ __forceinline__ float bfval(u16 b) { union { u32 u; float f; } c; c.u = (u32)b << 16; return c.f; }
__device__ __forceinline__ float bflo(u32 w) { union { u32 u; float f; } c; c.u = w << 16;         return c.f; }
__device__ __forceinline__ float bfhi(u32 w) { union { u32 u; float f; } c; c.u = w & 0xFFFF0000u; return c.f; }

// ---------------------------------------------------------------------------
// Kernel 1: fused q/k/v projection -> bf16. W chunks AND the F token-tile are
// staged in LDS; compute reads F as conflict-free ds_read_b128 broadcasts
// (round-5 profile: wave-uniform GLOBAL F loads left proj 85% latency-stalled).
// Accumulation order unchanged -> bit-identical to round-5 output.
// q,k stored [n][p][d]; v stored TRANSPOSED [n][d][p].
// ---------------------------------------------------------------------------
__global__ __launch_bounds__(256) void proj_kernel(
    const float* __restrict__ F,
    const float* __restrict__ Wq, const float* __restrict__ bq,
    const float* __restrict__ Wk, const float* __restrict__ bk,
    const float* __restrict__ Wv, const float* __restrict__ bv,
    u16* __restrict__ qo, u16* __restrict__ ko, u16* __restrict__ vto)
{
    __shared__ __align__(16) float Ws[3][DI][36];   // 27648 B
    __shared__ __align__(16) float Fs[32 * 68];     //  8704 B (32 c x 64 tok, pad 68)
    const int tid  = threadIdx.x;
    const int n    = blockIdx.x / NTILE;
    const int p0   = (blockIdx.x % NTILE) * 64;
    const int lane = tid & 63;                                   // = d
    const int wave = tid >> 6;
    const float* Fn = F + (size_t)n * CCH * HW;

    float aq[16], ak[16], av[16];
    const float bq_ = bq[lane], bk_ = bk[lane], bv_ = bv[lane];
    #pragma unroll
    for (int i = 0; i < 16; ++i) { aq[i] = bq_; ak[i] = bk_; av[i] = bv_; }

    for (int ch = 0; ch < 4; ++ch) {
        __syncthreads();                       // previous chunk fully consumed
        // stage W chunk (32 channels of each of Wq/Wk/Wv)
        for (int idx = tid; idx < DI * 32; idx += 256) {
            int d = idx >> 5, cc = idx & 31;
            int gsrc = d * CCH + ch * 32 + cc;
            Ws[0][d][cc] = Wq[gsrc];
            Ws[1][d][cc] = Wk[gsrc];
            Ws[2][d][cc] = Wv[gsrc];
        }
        // stage F chunk [32 c][64 tok], coalesced float4 reads
        #pragma unroll
        for (int s4 = 0; s4 < 2; ++s4) {
            int s   = tid + s4 * 256;          // float4 slot 0..511
            int row = s >> 4, col = (s & 15) * 4;
            *(float4*)&Fs[row * 68 + col] =
                *(const float4*)&Fn[(size_t)(ch * 32 + row) * HW + p0 + col];
        }
        __syncthreads();

        for (int c4 = 0; c4 < 8; ++c4) {
            float4 wq4 = *(const float4*)&Ws[0][lane][c4 * 4];
            float4 wk4 = *(const float4*)&Ws[1][lane][c4 * 4];
            float4 wv4 = *(const float4*)&Ws[2][lane][c4 * 4];
            #pragma unroll
            for (int i4 = 0; i4 < 4; ++i4) {
                float4 f0 = *(const float4*)&Fs[(c4 * 4 + 0) * 68 + wave * 16 + i4 * 4];
                float4 f1 = *(const float4*)&Fs[(c4 * 4 + 1) * 68 + wave * 16 + i4 * 4];
                float4 f2 = *(const float4*)&Fs[(c4 * 4 + 2) * 68 + wave * 16 + i4 * 4];
                float4 f3 = *(const float4*)&Fs[(c4 * 4 + 3) * 68 + wave * 16 + i4 * 4];
                #pragma unroll
                for (int j = 0; j < 4; ++j) {
                    int i = i4 * 4 + j;
                    float a = (&f0.x)[j], b = (&f1.x)[j], c = (&f2.x)[j], d = (&f3.x)[j];
                    aq[i] += a * wq4.x + b * wq4.y + c * wq4.z + d * wq4.w;
                    ak[i] += a * wk4.x + b * wk4.y + c * wk4.z + d * wk4.w;
                    av[i] += a * wv4.x + b * wv4.y + c * wv4.z + d * wv4.w;
                }
            }
        }
    }

    const int pbase = p0 + wave * 16;
    #pragma unroll
    for (int i = 0; i < 16; ++i) {
        size_t off = (size_t)(n * HW + pbase + i) * DI + lane;   // coalesced (d=lane)
        qo[off] = f2bf_rne(aq[i]);
        ko[off] = f2bf_rne(ak[i]);
    }
    union { u16 s[16]; uint4 v[2]; } pk;
    #pragma unroll
    for (int i = 0; i < 16; ++i) pk.s[i] = f2bf_rne(av[i]);
    size_t vo_off = ((size_t)n * DI + lane) * HW + pbase;
    *(uint4*)&vto[vo_off]     = pk.v[0];
    *(uint4*)&vto[vo_off + 8] = pk.v[1];
}

// ---------------------------------------------------------------------------
// Kernel 2: one-pass MFMA flash attention (no-max softmax). P stays entirely
// in registers WITHOUT cross-lane moves via the permuted K A-fragment rows
// kr_m(l) = 8(l>>2)+(l&3)+4(m&1)+32(m>>1)   (validated round 5).
// K,V double-buffered in swizzled LDS, one barrier per tile.
// This round: s_setprio(1) around the MFMA clusters (T5).
// ---------------------------------------------------------------------------
__global__ __launch_bounds__(256, 4) void attn_pass_kernel(
    const u16* __restrict__ q, const u16* __restrict__ k, const u16* __restrict__ vt,
    u16* __restrict__ ypart)
{
    __shared__ __align__(16) u16 smem[16384];     // 32 KiB: K dbuf | V dbuf
    u16* const Kb0 = smem;
    u16* const Kb1 = smem + 4096;
    u16* const Vb0 = smem + 8192;
    u16* const Vb1 = smem + 12288;

    const int tid  = threadIdx.x;
    const int lane = tid & 63;
    const int wave = tid >> 6;
    const int lo   = lane & 15, hi = lane >> 4;

    // chunked bijective XCD swizzle: 1152 = 8 * 144
    const int bid  = (int)blockIdx.x;
    const int w    = (bid & 7) * 144 + (bid >> 3);
    const int pass = w / (NBATCH * NTILE);
    const int rem  = w % (NBATCH * NTILE);
    const int n    = rem / NTILE;
    const int p0   = (rem % NTILE) * 64;

    const int nb = (pass == 0) ? (n > 0 ? n - 1 : 0)
                               : (n < NBATCH - 1 ? n + 1 : n);
    const u16* kp = k  + (size_t)nb * HW * DI;
    const u16* vp = vt + (size_t)nb * DI * HW;

    // Q fragments (B-operand of swapped QK): lane holds Q[q=lo][d=hi*8+j]
    bf16x8 qf0, qf1;
    {
        const u16* qp = q + ((size_t)n * HW + p0 + wave * 16 + lo) * DI + hi * 8;
        qf0 = *(const bf16x8*)qp;
        qf1 = *(const bf16x8*)(qp + 32);
    }

    // staging geometry: 512 x 16B chunks per 8KB tile; thread covers 2 rows
    const int sch   = tid & 7;                 // 16B chunk in row
    const int srow0 = tid >> 3;                // 0..31
    const int srow1 = srow0 + 32;
    const int fk0   = (srow0 & 3) | ((srow0 & 8) >> 1);
    const int fk1   = (srow1 & 3) | ((srow1 & 8) >> 1);
    const int koff0 = srow0 * 64 + ((sch ^ fk0) * 8);
    const int koff1 = srow1 * 64 + ((sch ^ fk1) * 8);
    const int voff0 = srow0 * 64 + ((sch ^ (srow0 & 7)) * 8);
    const int voff1 = srow1 * 64 + ((sch ^ (srow1 & 7)) * 8);

    // permuted K A-frag row base: kr_m = krbase + 4*(m&1) + 32*(m>>1)
    const int krbase = 8 * (lo >> 2) + (lo & 3);
    const int xl = lo & 7;                     // = fK(kr_m(lo)) = (V row)&7

    f32x4 yacc[4];
    #pragma unroll
    for (int nf = 0; nf < 4; ++nf)
        #pragma unroll
        for (int r = 0; r < 4; ++r) yacc[nf][r] = 0.f;
    float lacc = 0.f;

    // prologue: tile0 -> buf0; tile1 -> regs
    uint4 ka0 = *(const uint4*)(kp + (size_t)srow0 * DI + sch * 8);
    uint4 ka1 = *(const uint4*)(kp + (size_t)srow1 * DI + sch * 8);
    uint4 va0 = *(const uint4*)(vp + (size_t)srow0 * HW + sch * 8);
    uint4 va1 = *(const uint4*)(vp + (size_t)srow1 * HW + sch * 8);
    *(uint4*)&Kb0[koff0] = ka0;  *(uint4*)&Kb0[koff1] = ka1;
    *(uint4*)&Vb0[voff0] = va0;  *(uint4*)&Vb0[voff1] = va1;
    ka0 = *(const uint4*)(kp + (size_t)(64 + srow0) * DI + sch * 8);
    ka1 = *(const uint4*)(kp + (size_t)(64 + srow1) * DI + sch * 8);
    va0 = *(const uint4*)(vp + (size_t)srow0 * HW + 64 + sch * 8);
    va1 = *(const uint4*)(vp + (size_t)srow1 * HW + 64 + sch * 8);
    __syncthreads();

    auto body = [&](int t, const u16* Kc, const u16* Vc, u16* Kn, u16* Vn) {
        // --- swapped QK^T with permuted A rows ---
        // st[m][r] = S[key = 8hi + 4(m&1) + r + 32(m>>1)][q = lo]
        f32x4 st[4];
        __builtin_amdgcn_s_setprio(1);
        #pragma unroll
        for (int m = 0; m < 4; ++m) {
            const int kr = krbase + 4 * (m & 1) + 32 * (m >> 1);
            bf16x8 a0 = *(const bf16x8*)&Kc[kr * 64 + ((hi ^ xl) * 8)];
            bf16x8 a1 = *(const bf16x8*)&Kc[kr * 64 + (((4 + hi) ^ xl) * 8)];
            f32x4 z = {0.f, 0.f, 0.f, 0.f};
            z = __builtin_amdgcn_mfma_f32_16x16x32_bf16(a0, qf0, z, 0, 0, 0);
            z = __builtin_amdgcn_mfma_f32_16x16x32_bf16(a1, qf1, z, 0, 0, 0);
            st[m] = z;
        }
        __builtin_amdgcn_s_setprio(0);

        // --- P = exp(S), bf16 RNE pack in place (A-frag order);
        //     l accumulated from the rounded values (self-normalizing) ---
        W4 pa0, pa1;
        #pragma unroll
        for (int m = 0; m < 4; ++m) {
            u16 b0 = f2bf_rne(__expf(st[m][0]));
            u16 b1 = f2bf_rne(__expf(st[m][1]));
            u16 b2 = f2bf_rne(__expf(st[m][2]));
            u16 b3 = f2bf_rne(__expf(st[m][3]));
            lacc += (bfval(b0) + bfval(b1)) + (bfval(b2) + bfval(b3));
            u32 we = (u32)b0 | ((u32)b1 << 16);
            u32 wo = (u32)b2 | ((u32)b3 << 16);
            if (m == 0)      { pa0.w[0] = we; pa0.w[1] = wo; }
            else if (m == 1) { pa0.w[2] = we; pa0.w[3] = wo; }
            else if (m == 2) { pa1.w[0] = we; pa1.w[1] = wo; }
            else             { pa1.w[2] = we; pa1.w[3] = wo; }
        }

        // --- PV: Y[q][d] += P(16x64) x V(64k x 64d)  (B from V^T tile) ---
        __builtin_amdgcn_s_setprio(1);
        #pragma unroll
        for (int nf = 0; nf < 4; ++nf) {
            const int vr = nf * 16 + lo;
            bf16x8 v0 = *(const bf16x8*)&Vc[vr * 64 + ((hi ^ xl) * 8)];
            bf16x8 v1 = *(const bf16x8*)&Vc[vr * 64 + (((4 + hi) ^ xl) * 8)];
            yacc[nf] = __builtin_amdgcn_mfma_f32_16x16x32_bf16(pa0.v, v0, yacc[nf], 0, 0, 0);
            yacc[nf] = __builtin_amdgcn_mfma_f32_16x16x32_bf16(pa1.v, v1, yacc[nf], 0, 0, 0);
        }
        __builtin_amdgcn_s_setprio(0);

        // --- stage tile t+1 into the other buffer; prefetch t+2 ---
        if (t + 1 < NTILE) {
            *(uint4*)&Kn[koff0] = ka0; *(uint4*)&Kn[koff1] = ka1;
            *(uint4*)&Vn[voff0] = va0; *(uint4*)&Vn[voff1] = va1;
        }
        if (t + 2 < NTILE) {
            int tb = (t + 2) * 64;
            ka0 = *(const uint4*)(kp + (size_t)(tb + srow0) * DI + sch * 8);
            ka1 = *(const uint4*)(kp + (size_t)(tb + srow1) * DI + sch * 8);
            va0 = *(const uint4*)(vp + (size_t)srow0 * HW + tb + sch * 8);
            va1 = *(const uint4*)(vp + (size_t)srow1 * HW + tb + sch * 8);
        }
        __syncthreads();
    };

    #pragma unroll 1
    for (int tt = 0; tt < NTILE; tt += 2) {
        body(tt,     Kb0, Vb0, Kb1, Vb1);
        body(tt + 1, Kb1, Vb1, Kb0, Vb0);
    }

    // --- finalize: per-lane lacc covers keys {8hi..8hi+7, 32+8hi..} at q=lo;
    //     reduce over the hi dimension -> full l(q=lo) ---
    float l = lacc;
    l += __shfl_xor(l, 16);
    l += __shfl_xor(l, 32);
    float inv = 1.f / l;                       // valid for q = lo at every lane
    float invq[4];
    #pragma unroll
    for (int r = 0; r < 4; ++r) invq[r] = __shfl(inv, 20 * hi + r);  // q = 4hi+r

    __syncthreads();                           // done with K/V buffers
    u16* yw = smem;                            // [64][72] bf16 restage
    #pragma unroll
    for (int nf = 0; nf < 4; ++nf)
        #pragma unroll
        for (int r = 0; r < 4; ++r)
            yw[(wave * 16 + hi * 4 + r) * 72 + nf * 16 + lo] =
                f2bf_rne(yacc[nf][r] * invq[r]);
    __syncthreads();

    u16* yg = ypart + ((size_t)(pass * NBATCH + n) * HW + p0) * DI;
    #pragma unroll
    for (int s = 0; s < 2; ++s) {
        int idx = tid + s * 256;
        int row = idx >> 3, c8 = (idx & 7) * 8;
        *(uint4*)&yg[row * DI + c8] = *(const uint4*)&yw[row * 72 + c8];
    }
}

// ---------------------------------------------------------------------------
// Kernel 3: combine passes + fused z-projection + residual.
// z = (y_b + y_a) @ Wz^T + 2*bz + F                     (validated round 3)
// ---------------------------------------------------------------------------
__global__ __launch_bounds__(256) void combine_kernel(
    const u16* __restrict__ ypart, const float* __restrict__ Wz,
    const float* __restrict__ bz, const float* __restrict__ F,
    float* __restrict__ out)
{
    __shared__ __align__(16) float ys[64 * 68];
    const int tid = threadIdx.x;
    const int n   = blockIdx.x / NTILE;
    const int p0  = (blockIdx.x % NTILE) * 64;
    const u16* y0 = ypart + ((size_t)n * HW + p0) * DI;
    const u16* y1 = ypart + ((size_t)(NBATCH + n) * HW + p0) * DI;

    #pragma unroll
    for (int s = 0; s < 2; ++s) {
        int idx = tid + s * 256;
        int row = idx >> 3, c8 = (idx & 7) * 8;
        uint4 a = *(const uint4*)&y0[row * DI + c8];
        uint4 b = *(const uint4*)&y1[row * DI + c8];
        const u32 au[4] = {a.x, a.y, a.z, a.w};
        const u32 bu[4] = {b.x, b.y, b.z, b.w};
        float* d = &ys[row * 68 + c8];
        #pragma unroll
        for (int e = 0; e < 4; ++e) {
            d[e * 2]     = bflo(au[e]) + bflo(bu[e]);
            d[e * 2 + 1] = bfhi(au[e]) + bfhi(bu[e]);
        }
    }
    __syncthreads();

    const int lane = tid & 63;
    const int wave = tid >> 6;
    float acc[32];
    #pragma unroll
    for (int i = 0; i < 32; ++i) acc[i] = 0.f;
    #pragma unroll
    for (int d4 = 0; d4 < 16; ++d4) {
        float4 yy = *(const float4*)&ys[lane * 68 + d4 * 4];
        #pragma unroll 8
        for (int i = 0; i < 32; ++i) {
            int c = wave + 4 * i;                  // wave-uniform -> scalar Wz loads
            float4 ww = *(const float4*)&Wz[c * DI + d4 * 4];
            acc[i] += yy.x * ww.x + yy.y * ww.y + yy.z * ww.z + yy.w * ww.w;
        }
    }
    #pragma unroll 4
    for (int i = 0; i < 32; ++i) {
        int c = wave + 4 * i;
        size_t gi = (size_t)(n * CCH + c) * HW + p0 + lane;
        out[gi] = acc[i] + 2.f * bz[c] + F[gi];    // coalesced store + residual
    }
}

extern "C" void kernel_launch(void* const* d_in, const int* in_sizes, int n_in,
                              void* d_out, int out_size, void* d_ws, size_t ws_size,
                              hipStream_t stream) {
    const float* F  = (const float*)d_in[0];
    const float* Wq = (const float*)d_in[1];
    const float* bq = (const float*)d_in[2];
    const float* Wk = (const float*)d_in[3];
    const float* bk = (const float*)d_in[4];
    const float* Wv = (const float*)d_in[5];
    const float* bv = (const float*)d_in[6];
    const float* Wz = (const float*)d_in[7];
    const float* bz = (const float*)d_in[8];
    float* outp = (float*)d_out;

    const size_t tok = (size_t)NBATCH * HW * DI;   // 2,359,296 elements
    u16* qb  = (u16*)d_ws;
    u16* kb  = qb  + tok;
    u16* vtb = kb  + tok;
    u16* yp  = vtb + tok;                          // 2*tok bf16 partials
    // total ws: 5 * tok * 2B = 23.6 MB

    proj_kernel<<<NBATCH * NTILE, 256, 0, stream>>>(F, Wq, bq, Wk, bk, Wv, bv, qb, kb, vtb);
    attn_pass_kernel<<<2 * NBATCH * NTILE, 256, 0, stream>>>(qb, kb, vtb, yp);
    combine_kernel<<<NBATCH * NTILE, 256, 0, stream>>>(yp, Wz, bz, F, outp);
}

// Round 7
// 168.609 us; speedup vs baseline: 1.8540x; 1.1725x over previous
//
#include <hip/hip_runtime.h>
#include <math.h>

// Problem constants (fixed by the reference)
#define NBATCH 16
#define CCH    128     // channels C
#define HW     2304    // 48*48 tokens per frame
#define DI     64      // inter_channels CI
#define NTILE  36      // HW / 64 (64-token tiles: proj/combine blocks, attn KEY tiles)
#define QTILE  18      // HW / 128 (attn q-blocks)

typedef unsigned short u16;
typedef unsigned int   u32;
typedef __bf16   bf16x8 __attribute__((ext_vector_type(8)));
typedef _Float16 f16x8  __attribute__((ext_vector_type(8)));
typedef float    f32x4  __attribute__((ext_vector_type(4)));

union W4 { u32 w[4]; bf16x8 v; };

__device__ __forceinline__ u16 f2bf_rne(float x) {
    union { float f; u32 u; } v; v.f = x;
    u32 r = (v.u + 0x7FFFu + ((v.u >> 16) & 1u)) >> 16;
    return (u16)r;
}
__device__ __forceinline__ u16 f2h(float x) {
    union { _Float16 h; u16 u; } c; c.h = (_Float16)x; return c.u;
}
__device__ __forceinline__ float bfval(u16 b) { union { u32 u; float f; } c; c.u = (u32)b << 16; return c.f; }
__device__ __forceinline__ float bflo(u32 w) { union { u32 u; float f; } c; c.u = w << 16;         return c.f; }
__device__ __forceinline__ float bfhi(u32 w) { union { u32 u; float f; } c; c.u = w & 0xFFFF0000u; return c.f; }

// ---------------------------------------------------------------------------
// Kernel 1: q/k/v projection as one fp16 MFMA GEMM per 64-token block:
// [64 tok x 128 c] x [128 c x 192 out] -> q,k (fp16, [n][p][d]) and
// v (bf16, TRANSPOSED [n][d][p], restaged via LDS for coalesced stores).
// F and W staged in LDS fp16 with chunk-XOR swizzle (per-lane frag reads —
// fixes round-6's 16-useful-bytes-per-broadcast LDS pattern).
// ---------------------------------------------------------------------------
__global__ __launch_bounds__(256) void proj_kernel(
    const float* __restrict__ F,
    const float* __restrict__ Wq, const float* __restrict__ bq,
    const float* __restrict__ Wk, const float* __restrict__ bk,
    const float* __restrict__ Wv, const float* __restrict__ bv,
    u16* __restrict__ qo, u16* __restrict__ ko, u16* __restrict__ vto)
{
    __shared__ __align__(16) u16 Wl[192 * 128];   // 49152 B fp16 [dout][c], swizzled
    __shared__ __align__(16) u16 Fl[64 * 128];    // 16384 B fp16 [tok][c], swizzled
    __shared__ __align__(16) u16 Vt[64 * 72];     //  9216 B bf16 v^T restage

    const int tid  = threadIdx.x;
    const int n    = blockIdx.x / NTILE;
    const int p0   = (blockIdx.x % NTILE) * 64;
    const int lane = tid & 63, wave = tid >> 6;
    const int lo   = lane & 15, hi = lane >> 4;

    // --- stage W (fp32 -> fp16): rows 0-63 Wq, 64-127 Wk, 128-191 Wv ---
    #pragma unroll
    for (int i = 0; i < 12; ++i) {
        int s = tid + i * 256;                    // chunk id 0..3071
        int row = s >> 4, ch = s & 15;
        const float* src = (row < 64)  ? &Wq[row * CCH]
                         : (row < 128) ? &Wk[(row - 64) * CCH]
                                       : &Wv[(row - 128) * CCH];
        float4 a = *(const float4*)&src[ch * 8];
        float4 b = *(const float4*)&src[ch * 8 + 4];
        union { u16 s8[8]; uint4 v; } pk;
        pk.s8[0] = f2h(a.x); pk.s8[1] = f2h(a.y); pk.s8[2] = f2h(a.z); pk.s8[3] = f2h(a.w);
        pk.s8[4] = f2h(b.x); pk.s8[5] = f2h(b.y); pk.s8[6] = f2h(b.z); pk.s8[7] = f2h(b.w);
        *(uint4*)&Wl[row * 128 + ((ch ^ (row & 15)) << 3)] = pk.v;
    }
    // --- stage F transposed [tok][c] (fp32 -> fp16), packed u32 writes ---
    const float* Fn = F + (size_t)n * CCH * HW;
    #pragma unroll
    for (int i = 0; i < 4; ++i) {
        int s  = tid + i * 256;                   // 0..1023
        int c0 = (s >> 4) * 2;                    // even channel
        int t0 = (s & 15) * 4;                    // token group
        const float* fp_ = &Fn[(size_t)c0 * HW + p0 + t0];
        float4 fa = *(const float4*)fp_;
        float4 fb = *(const float4*)(fp_ + HW);
        #pragma unroll
        for (int e = 0; e < 4; ++e) {
            int t = t0 + e;
            u32 w = (u32)f2h((&fa.x)[e]) | ((u32)f2h((&fb.x)[e]) << 16);
            *(u32*)&Fl[t * 128 + (((c0 >> 3) ^ (t & 15)) << 3) + (c0 & 7)] = w;
        }
    }
    __syncthreads();

    // --- A-frags: F rows = tokens wave*16 + lo ---
    const int arow = wave * 16 + lo;
    f16x8 af[4];
    #pragma unroll
    for (int ks = 0; ks < 4; ++ks)
        af[ks] = *(const f16x8*)&Fl[arow * 128 + (((ks * 4 + hi) ^ lo) << 3)];

    f32x4 acc[12];
    #pragma unroll
    for (int g = 0; g < 12; ++g)
        #pragma unroll
        for (int r = 0; r < 4; ++r) acc[g][r] = 0.f;

    #pragma unroll
    for (int g = 0; g < 12; ++g) {
        #pragma unroll
        for (int ks = 0; ks < 4; ++ks) {
            f16x8 bf = *(const f16x8*)&Wl[(g * 16 + lo) * 128 + (((ks * 4 + hi) ^ lo) << 3)];
            acc[g] = __builtin_amdgcn_mfma_f32_16x16x32_f16(af[ks], bf, acc[g], 0, 0, 0);
        }
    }

    // --- epilogue: D[row = token 4hi+r][col = dout g*16+lo] ---
    const int twb = p0 + wave * 16 + 4 * hi;      // + r = global token
    #pragma unroll
    for (int g = 0; g < 4; ++g) {
        float bQ = bq[g * 16 + lo], bK = bk[g * 16 + lo];
        #pragma unroll
        for (int r = 0; r < 4; ++r) {
            size_t off = ((size_t)n * HW + twb + r) * DI + g * 16 + lo;
            qo[off] = f2h(acc[g][r] + bQ);
            ko[off] = f2h(acc[g + 4][r] + bK);
        }
    }
    #pragma unroll
    for (int g = 0; g < 4; ++g) {
        float bV = bv[g * 16 + lo];
        #pragma unroll
        for (int r = 0; r < 4; ++r)
            Vt[(g * 16 + lo) * 72 + wave * 16 + 4 * hi + r] = f2bf_rne(acc[g + 8][r] + bV);
    }
    __syncthreads();
    #pragma unroll
    for (int i = 0; i < 2; ++i) {
        int s = tid + i * 256;                    // 0..511
        int d = s >> 3, c8 = (s & 7) * 8;
        *(uint4*)&vto[((size_t)n * DI + d) * HW + p0 + c8] = *(const uint4*)&Vt[d * 72 + c8];
    }
}

// ---------------------------------------------------------------------------
// Kernel 2: one-pass MFMA flash attention (no-max softmax), Q=32 rows/wave
// (128-row blocks — halves LDS frag+staging traffic per q-row vs round 6).
// QK^T in fp16 (q,k fp16); P in registers via the validated κ-permuted
// K-row trick, packed to bf16; PV in bf16. K,V double-buffered in swizzled
// LDS, one barrier per tile.  Grid 576 = 2 passes x 16 frames x 18 q-blocks.
// ---------------------------------------------------------------------------
__global__ __launch_bounds__(256, 3) void attn_pass_kernel(
    const u16* __restrict__ q, const u16* __restrict__ k, const u16* __restrict__ vt,
    u16* __restrict__ ypart)
{
    __shared__ __align__(16) u16 smem[16384];     // 32 KiB: K dbuf (fp16) | V dbuf (bf16)
    u16* const Kb0 = smem;
    u16* const Kb1 = smem + 4096;
    u16* const Vb0 = smem + 8192;
    u16* const Vb1 = smem + 12288;

    const int tid  = threadIdx.x;
    const int lane = tid & 63;
    const int wave = tid >> 6;
    const int lo   = lane & 15, hi = lane >> 4;

    // chunked bijective XCD swizzle: 576 = 8 * 72
    const int bid  = (int)blockIdx.x;
    const int w    = (bid & 7) * 72 + (bid >> 3);
    const int pass = w / (NBATCH * QTILE);
    const int rem  = w % (NBATCH * QTILE);
    const int n    = rem / QTILE;
    const int p0   = (rem % QTILE) * 128;

    const int nb = (pass == 0) ? (n > 0 ? n - 1 : 0)
                               : (n < NBATCH - 1 ? n + 1 : n);
    const u16* kp = k  + (size_t)nb * HW * DI;
    const u16* vp = vt + (size_t)nb * DI * HW;

    // Q fragments (B-operand of swapped QK), two 16-row sets per wave
    f16x8 qfA0, qfA1, qfB0, qfB1;
    {
        const u16* qp = q + ((size_t)n * HW + p0 + wave * 32 + lo) * DI + hi * 8;
        qfA0 = *(const f16x8*)qp;
        qfA1 = *(const f16x8*)(qp + 32);
        qfB0 = *(const f16x8*)(qp + 16 * DI);
        qfB1 = *(const f16x8*)(qp + 16 * DI + 32);
    }

    // staging geometry: 512 x 16B chunks per 8KB tile; thread covers 2 rows
    const int sch   = tid & 7;
    const int srow0 = tid >> 3;
    const int srow1 = srow0 + 32;
    const int fk0   = (srow0 & 3) | ((srow0 & 8) >> 1);
    const int fk1   = (srow1 & 3) | ((srow1 & 8) >> 1);
    const int koff0 = srow0 * 64 + ((sch ^ fk0) * 8);
    const int koff1 = srow1 * 64 + ((sch ^ fk1) * 8);
    const int voff0 = srow0 * 64 + ((sch ^ (srow0 & 7)) * 8);
    const int voff1 = srow1 * 64 + ((sch ^ (srow1 & 7)) * 8);

    // permuted K A-frag row base: kr_m = krbase + 4*(m&1) + 32*(m>>1)
    const int krbase = 8 * (lo >> 2) + (lo & 3);
    const int xl = lo & 7;

    f32x4 yaccA[4], yaccB[4];
    #pragma unroll
    for (int nf = 0; nf < 4; ++nf)
        #pragma unroll
        for (int r = 0; r < 4; ++r) { yaccA[nf][r] = 0.f; yaccB[nf][r] = 0.f; }
    float laccA = 0.f, laccB = 0.f;

    // prologue: tile0 -> buf0; tile1 -> regs
    uint4 ka0 = *(const uint4*)(kp + (size_t)srow0 * DI + sch * 8);
    uint4 ka1 = *(const uint4*)(kp + (size_t)srow1 * DI + sch * 8);
    uint4 va0 = *(const uint4*)(vp + (size_t)srow0 * HW + sch * 8);
    uint4 va1 = *(const uint4*)(vp + (size_t)srow1 * HW + sch * 8);
    *(uint4*)&Kb0[koff0] = ka0;  *(uint4*)&Kb0[koff1] = ka1;
    *(uint4*)&Vb0[voff0] = va0;  *(uint4*)&Vb0[voff1] = va1;
    ka0 = *(const uint4*)(kp + (size_t)(64 + srow0) * DI + sch * 8);
    ka1 = *(const uint4*)(kp + (size_t)(64 + srow1) * DI + sch * 8);
    va0 = *(const uint4*)(vp + (size_t)srow0 * HW + 64 + sch * 8);
    va1 = *(const uint4*)(vp + (size_t)srow1 * HW + 64 + sch * 8);
    __syncthreads();

    auto body = [&](int t, const u16* Kc, const u16* Vc, u16* Kn, u16* Vn) {
        // --- swapped QK^T with permuted A rows (both q-sets share K frags) ---
        f32x4 stA[4], stB[4];
        __builtin_amdgcn_s_setprio(1);
        #pragma unroll
        for (int m = 0; m < 4; ++m) {
            const int kr = krbase + 4 * (m & 1) + 32 * (m >> 1);
            f16x8 a0 = *(const f16x8*)&Kc[kr * 64 + ((hi ^ xl) * 8)];
            f16x8 a1 = *(const f16x8*)&Kc[kr * 64 + (((4 + hi) ^ xl) * 8)];
            f32x4 zA = {0.f, 0.f, 0.f, 0.f};
            zA = __builtin_amdgcn_mfma_f32_16x16x32_f16(a0, qfA0, zA, 0, 0, 0);
            zA = __builtin_amdgcn_mfma_f32_16x16x32_f16(a1, qfA1, zA, 0, 0, 0);
            stA[m] = zA;
            f32x4 zB = {0.f, 0.f, 0.f, 0.f};
            zB = __builtin_amdgcn_mfma_f32_16x16x32_f16(a0, qfB0, zB, 0, 0, 0);
            zB = __builtin_amdgcn_mfma_f32_16x16x32_f16(a1, qfB1, zB, 0, 0, 0);
            stB[m] = zB;
        }
        __builtin_amdgcn_s_setprio(0);

        // --- P = exp(S) -> bf16 RNE (A-frag order); l from rounded values ---
        W4 paA0, paA1, paB0, paB1;
        #pragma unroll
        for (int m = 0; m < 4; ++m) {
            u16 b0 = f2bf_rne(__expf(stA[m][0]));
            u16 b1 = f2bf_rne(__expf(stA[m][1]));
            u16 b2 = f2bf_rne(__expf(stA[m][2]));
            u16 b3 = f2bf_rne(__expf(stA[m][3]));
            laccA += (bfval(b0) + bfval(b1)) + (bfval(b2) + bfval(b3));
            u32 we = (u32)b0 | ((u32)b1 << 16);
            u32 wo = (u32)b2 | ((u32)b3 << 16);
            if (m == 0)      { paA0.w[0] = we; paA0.w[1] = wo; }
            else if (m == 1) { paA0.w[2] = we; paA0.w[3] = wo; }
            else if (m == 2) { paA1.w[0] = we; paA1.w[1] = wo; }
            else             { paA1.w[2] = we; paA1.w[3] = wo; }
        }
        #pragma unroll
        for (int m = 0; m < 4; ++m) {
            u16 b0 = f2bf_rne(__expf(stB[m][0]));
            u16 b1 = f2bf_rne(__expf(stB[m][1]));
            u16 b2 = f2bf_rne(__expf(stB[m][2]));
            u16 b3 = f2bf_rne(__expf(stB[m][3]));
            laccB += (bfval(b0) + bfval(b1)) + (bfval(b2) + bfval(b3));
            u32 we = (u32)b0 | ((u32)b1 << 16);
            u32 wo = (u32)b2 | ((u32)b3 << 16);
            if (m == 0)      { paB0.w[0] = we; paB0.w[1] = wo; }
            else if (m == 1) { paB0.w[2] = we; paB0.w[3] = wo; }
            else if (m == 2) { paB1.w[0] = we; paB1.w[1] = wo; }
            else             { paB1.w[2] = we; paB1.w[3] = wo; }
        }

        // --- PV: both q-sets share V frags ---
        __builtin_amdgcn_s_setprio(1);
        #pragma unroll
        for (int nf = 0; nf < 4; ++nf) {
            const int vr = nf * 16 + lo;
            bf16x8 v0 = *(const bf16x8*)&Vc[vr * 64 + ((hi ^ xl) * 8)];
            bf16x8 v1 = *(const bf16x8*)&Vc[vr * 64 + (((4 + hi) ^ xl) * 8)];
            yaccA[nf] = __builtin_amdgcn_mfma_f32_16x16x32_bf16(paA0.v, v0, yaccA[nf], 0, 0, 0);
            yaccA[nf] = __builtin_amdgcn_mfma_f32_16x16x32_bf16(paA1.v, v1, yaccA[nf], 0, 0, 0);
            yaccB[nf] = __builtin_amdgcn_mfma_f32_16x16x32_bf16(paB0.v, v0, yaccB[nf], 0, 0, 0);
            yaccB[nf] = __builtin_amdgcn_mfma_f32_16x16x32_bf16(paB1.v, v1, yaccB[nf], 0, 0, 0);
        }
        __builtin_amdgcn_s_setprio(0);

        // --- stage tile t+1; prefetch t+2 ---
        if (t + 1 < NTILE) {
            *(uint4*)&Kn[koff0] = ka0; *(uint4*)&Kn[koff1] = ka1;
            *(uint4*)&Vn[voff0] = va0; *(uint4*)&Vn[voff1] = va1;
        }
        if (t + 2 < NTILE) {
            int tb = (t + 2) * 64;
            ka0 = *(const uint4*)(kp + (size_t)(tb + srow0) * DI + sch * 8);
            ka1 = *(const uint4*)(kp + (size_t)(tb + srow1) * DI + sch * 8);
            va0 = *(const uint4*)(vp + (size_t)srow0 * HW + tb + sch * 8);
            va1 = *(const uint4*)(vp + (size_t)srow1 * HW + tb + sch * 8);
        }
        __syncthreads();
    };

    #pragma unroll 1
    for (int tt = 0; tt < NTILE; tt += 2) {
        body(tt,     Kb0, Vb0, Kb1, Vb1);
        body(tt + 1, Kb1, Vb1, Kb0, Vb0);
    }

    // --- finalize (per set): reduce l over hi-groups, per-row inv ---
    float lA = laccA;
    lA += __shfl_xor(lA, 16);
    lA += __shfl_xor(lA, 32);
    float invA = 1.f / lA;
    float lB = laccB;
    lB += __shfl_xor(lB, 16);
    lB += __shfl_xor(lB, 32);
    float invB = 1.f / lB;
    float invqA[4], invqB[4];
    #pragma unroll
    for (int r = 0; r < 4; ++r) {
        invqA[r] = __shfl(invA, 20 * hi + r);     // q = 4hi+r (set A)
        invqB[r] = __shfl(invB, 20 * hi + r);
    }

    __syncthreads();                              // done with K/V buffers
    u16* yw = smem;                               // [128][72] bf16 restage
    #pragma unroll
    for (int nf = 0; nf < 4; ++nf)
        #pragma unroll
        for (int r = 0; r < 4; ++r) {
            yw[(wave * 32 + 4 * hi + r) * 72 + nf * 16 + lo]      = f2bf_rne(yaccA[nf][r] * invqA[r]);
            yw[(wave * 32 + 16 + 4 * hi + r) * 72 + nf * 16 + lo] = f2bf_rne(yaccB[nf][r] * invqB[r]);
        }
    __syncthreads();

    u16* yg = ypart + ((size_t)(pass * NBATCH + n) * HW + p0) * DI;
    #pragma unroll
    for (int s4 = 0; s4 < 4; ++s4) {
        int idx = tid + s4 * 256;                 // 1024 x 16B chunks (128 rows)
        int row = idx >> 3, c8 = (idx & 7) * 8;
        *(uint4*)&yg[row * DI + c8] = *(const uint4*)&yw[row * 72 + c8];
    }
}

// ---------------------------------------------------------------------------
// Kernel 3: combine passes + fused z-projection + residual.
// z = (y_b + y_a) @ Wz^T + 2*bz + F                     (validated round 3)
// ---------------------------------------------------------------------------
__global__ __launch_bounds__(256) void combine_kernel(
    const u16* __restrict__ ypart, const float* __restrict__ Wz,
    const float* __restrict__ bz, const float* __restrict__ F,
    float* __restrict__ out)
{
    __shared__ __align__(16) float ys[64 * 68];
    const int tid = threadIdx.x;
    const int n   = blockIdx.x / NTILE;
    const int p0  = (blockIdx.x % NTILE) * 64;
    const u16* y0 = ypart + ((size_t)n * HW + p0) * DI;
    const u16* y1 = ypart + ((size_t)(NBATCH + n) * HW + p0) * DI;

    #pragma unroll
    for (int s = 0; s < 2; ++s) {
        int idx = tid + s * 256;
        int row = idx >> 3, c8 = (idx & 7) * 8;
        uint4 a = *(const uint4*)&y0[row * DI + c8];
        uint4 b = *(const uint4*)&y1[row * DI + c8];
        const u32 au[4] = {a.x, a.y, a.z, a.w};
        const u32 bu[4] = {b.x, b.y, b.z, b.w};
        float* d = &ys[row * 68 + c8];
        #pragma unroll
        for (int e = 0; e < 4; ++e) {
            d[e * 2]     = bflo(au[e]) + bflo(bu[e]);
            d[e * 2 + 1] = bfhi(au[e]) + bfhi(bu[e]);
        }
    }
    __syncthreads();

    const int lane = tid & 63;
    const int wave = tid >> 6;
    float acc[32];
    #pragma unroll
    for (int i = 0; i < 32; ++i) acc[i] = 0.f;
    #pragma unroll
    for (int d4 = 0; d4 < 16; ++d4) {
        float4 yy = *(const float4*)&ys[lane * 68 + d4 * 4];
        #pragma unroll 8
        for (int i = 0; i < 32; ++i) {
            int c = wave + 4 * i;                  // wave-uniform -> scalar Wz loads
            float4 ww = *(const float4*)&Wz[c * DI + d4 * 4];
            acc[i] += yy.x * ww.x + yy.y * ww.y + yy.z * ww.z + yy.w * ww.w;
        }
    }
    #pragma unroll 4
    for (int i = 0; i < 32; ++i) {
        int c = wave + 4 * i;
        size_t gi = (size_t)(n * CCH + c) * HW + p0 + lane;
        out[gi] = acc[i] + 2.f * bz[c] + F[gi];    // coalesced store + residual
    }
}

extern "C" void kernel_launch(void* const* d_in, const int* in_sizes, int n_in,
                              void* d_out, int out_size, void* d_ws, size_t ws_size,
                              hipStream_t stream) {
    const float* F  = (const float*)d_in[0];
    const float* Wq = (const float*)d_in[1];
    const float* bq = (const float*)d_in[2];
    const float* Wk = (const float*)d_in[3];
    const float* bk = (const float*)d_in[4];
    const float* Wv = (const float*)d_in[5];
    const float* bv = (const float*)d_in[6];
    const float* Wz = (const float*)d_in[7];
    const float* bz = (const float*)d_in[8];
    float* outp = (float*)d_out;

    const size_t tok = (size_t)NBATCH * HW * DI;   // 2,359,296 elements
    u16* qb  = (u16*)d_ws;                         // fp16
    u16* kb  = qb  + tok;                          // fp16
    u16* vtb = kb  + tok;                          // bf16, transposed
    u16* yp  = vtb + tok;                          // 2*tok bf16 partials
    // total ws: 5 * tok * 2B = 23.6 MB

    proj_kernel<<<NBATCH * NTILE, 256, 0, stream>>>(F, Wq, bq, Wk, bk, Wv, bv, qb, kb, vtb);
    attn_pass_kernel<<<2 * NBATCH * QTILE, 256, 0, stream>>>(qb, kb, vtb, yp);
    combine_kernel<<<NBATCH * NTILE, 256, 0, stream>>>(yp, Wz, bz, F, outp);
}